// Round 6
// baseline (114.804 us; speedup 1.0000x reference)
//
#include <hip/hip_runtime.h>

typedef _Float16 half8 __attribute__((ext_vector_type(8)));
typedef float f32x4 __attribute__((ext_vector_type(4)));
typedef float f32x16 __attribute__((ext_vector_type(16)));

union H8 { half8 h; float4 f; };
union F4 { float4 f; f32x4 v; };

#define EDIM 128
#define CDIM 128
#define HDIM 100
#define ODIM 104

// workspace offsets (bytes), all 256-aligned; total = 14,102,528 bytes
#define OFF_WFRAG  0u          // W_lin B-frags (16x16x32):   8*4*64*8*2  = 32768
#define OFF_WIH    32768u      // wih A-frags (32x32x16):  2*12*8*64*8*2  = 196608
#define OFF_WHH    229376u     // whh B-frags (16x16x32):  2*21*4*64*8*2  = 172032
#define OFF_BIASP  401408u     // gi bias (bih + bhh_{r,z}): 2*384*4      = 3072
#define OFF_BHHN   404480u     // (unused)                                = 1024
#define OFF_STMT   405504u     // stmt f16 [t*64+b][128]:    4096*128*2   = 1048576
#define OFF_GI     1454080u    // gi fp32 [dir][t][col][b]: 2*64*384*64*4 = 12582912
#define OFF_POOL   14036992u   // pooled fp32: 2*64*128*4                 = 65536

__device__ inline f32x4 zero4() { f32x4 z = {0.f, 0.f, 0.f, 0.f}; return z; }
__device__ inline float sigmoidf_fast(float x) {
  return __fdividef(1.f, 1.f + __expf(-x));
}
__device__ inline float tanhf_fast(float x) {
  float e2 = __expf(2.f * x);
  return 1.f - __fdividef(2.f, e2 + 1.f);
}

// ---------------------------------------------------------------------------
// K0: convert weights to f16 MFMA fragment layouts + fold biases (runs every call)
// ---------------------------------------------------------------------------
__global__ __launch_bounds__(256) void astnn_prep(
    const float* __restrict__ W_lin,
    const float* __restrict__ wihf, const float* __restrict__ whhf,
    const float* __restrict__ bihf, const float* __restrict__ bhhf,
    const float* __restrict__ wihb, const float* __restrict__ whhb,
    const float* __restrict__ bihb, const float* __restrict__ bhhb,
    _Float16* __restrict__ wfrag, _Float16* __restrict__ wihfrag,
    _Float16* __restrict__ whhfrag, float* __restrict__ biasP)
{
  int gid = blockIdx.x * 256 + threadIdx.x;
  if (gid < 2048) {
    // W_lin -> 16x16x32 B-frags: B[k][n], lane l: n=l&15, k=kc*32+((l>>4)<<3)+e
    int i = gid, l = i & 63, kc = (i >> 6) & 3, nt = i >> 8;
    int n = (nt << 4) + (l & 15);
    int kb = (kc << 5) + ((l >> 4) << 3);
#pragma unroll
    for (int e = 0; e < 8; e++)
      wfrag[i * 8 + e] = (_Float16)W_lin[(kb + e) * CDIM + n];
  } else if (gid < 14336) {
    // wih -> 32x32x16 frags usable as A (m=l&31, k=kc*16+((l>>5)<<3)+e):
    // value = wih[col=m][k]; cols padded per-section to 128 (12 tiles of 32)
    int i = gid - 2048, l = i & 63, kc = (i >> 6) & 7;
    int rest = i >> 9, nt = rest % 12, d = rest / 12;
    const float* wih = d ? wihb : wihf;
    int n = (nt << 5) + (l & 31), s = n >> 7, j = n & 127;
    int kb = (kc << 4) + ((l >> 5) << 3);
#pragma unroll
    for (int e = 0; e < 8; e++) {
      float v = (j < HDIM) ? wih[(s * HDIM + j) * CDIM + (kb + e)] : 0.f;
      wihfrag[i * 8 + e] = (_Float16)v;
    }
  } else if (gid < 25088) {
    // whh -> 16x16x32 B-frags: lane l: n=l&15, k=kc*32+((l>>4)<<3)+e
    // N padded per-section to 112 (3*112=336, 21 tiles of 16), K padded to 128
    // k==HDIM row of the n-section (s==2) carries bhh_n (h col 100 is const 1.0)
    int i = gid - 14336, l = i & 63, kc = (i >> 6) & 3;
    int rest = i >> 8, nt = rest % 21, d = rest / 21;
    const float* whh = d ? whhb : whhf;
    const float* bhh = d ? bhhb : bhhf;
    int n = (nt << 4) + (l & 15), s = n / 112, j = n - 112 * s;
    int kb = (kc << 5) + ((l >> 4) << 3);
#pragma unroll
    for (int e = 0; e < 8; e++) {
      int k = kb + e;
      float v = 0.f;
      if (j < HDIM) {
        if (k < HDIM) v = whh[(s * HDIM + j) * HDIM + k];
        else if (k == HDIM && s == 2) v = bhh[2 * HDIM + j];
      }
      whhfrag[i * 8 + e] = (_Float16)v;
    }
  } else if (gid < 25856) {
    // biasP[d][384] = bih[g] + (s<2 ? bhh[g] : 0), pad = 0
    int i = gid - 25088, d = i / 384, col = i % 384, s = col >> 7, j = col & 127;
    const float* bih = d ? bihb : bihf;
    const float* bhh = d ? bhhb : bhhf;
    float v = 0.f;
    if (j < HDIM) { v = bih[s * HDIM + j]; if (s < 2) v += bhh[s * HDIM + j]; }
    biasP[i] = v;
  }
}

// ---------------------------------------------------------------------------
// K1: per-block 4 trees (128 nodes): gather emb -> f16 LDS, MFMA x W_lin (+b),
//     subtree-sum via ancestor-bitmask MFMA, max-pool -> stmt (f16).
//     stmt stored in row' = t*64 + b order (tree g = b*64+t).
// ---------------------------------------------------------------------------
__global__ __launch_bounds__(256, 2) void astnn_tree(
    const int* __restrict__ node_ids, const int* __restrict__ parent,
    const float* __restrict__ emb, const float* __restrict__ b_lin,
    const _Float16* __restrict__ wfrag, _Float16* __restrict__ stmt)
{
  __shared__ _Float16 ldsW[16384];   // 32KB: W B-frags (linear frag order)
  __shared__ _Float16 ldsA[16384];   // 32KB: emb tile (swizzled), reused for h-frags
  __shared__ int ldsPar[128];
  __shared__ unsigned ldsAnc[128];

  const int t = threadIdx.x, blk = blockIdx.x;
  const int w = t >> 6, l = t & 63;
  const int base = blk * 128;

  if (t < 128) ldsPar[t] = parent[base + t] & 31;  // trees are 32-aligned globally

  {  // stage W fragments (32KB linear copy)
    const float4* wsrc = (const float4*)wfrag;
#pragma unroll
    for (int i = 0; i < 8; i++) ((float4*)ldsW)[i * 256 + t] = wsrc[i * 256 + t];
  }

  {  // gather embedding rows -> f16, swizzled row-major [128][128]
    const int r = t >> 1, hf = t & 1;
    const int nid = node_ids[base + r];
    const float4* erow = (const float4*)(emb + (size_t)nid * EDIM) + hf * 16;
#pragma unroll
    for (int b2 = 0; b2 < 2; b2++) {
      float4 stage[8];
#pragma unroll
      for (int i = 0; i < 8; i++) stage[i] = erow[b2 * 8 + i];
#pragma unroll
      for (int c4 = 0; c4 < 4; c4++) {
        H8 u;
#pragma unroll
        for (int e = 0; e < 8; e++)
          u.h[e] = (_Float16)(((const float*)&stage[0])[c4 * 8 + e]);
        int c = b2 * 4 + c4;
        int addr = (r * 256 + hf * 128 + c * 16) ^ ((r & 7) << 4);
        *(float4*)((char*)ldsA + addr) = u.f;
      }
    }
  }
  __syncthreads();

  // ancestor-mask build: A[n] = ancestors-or-self bitmask (chain walk, depth<=10)
  if (t < 128) {
    int tree = t >> 5;
    unsigned mask = 0;
    int cur = t & 31;
#pragma unroll
    for (int it = 0; it < 11; ++it) { mask |= (1u << cur); cur = ldsPar[tree * 32 + cur]; }
    ldsAnc[t] = mask;
  }
  __syncthreads();

  // GEMM: h[128][128] = emb_tile @ W  (16x16x32 f16), wave w owns M-tiles 2w,2w+1
  f32x4 acc[2][8];
#pragma unroll
  for (int mt = 0; mt < 2; mt++)
#pragma unroll
    for (int nt = 0; nt < 8; nt++) acc[mt][nt] = zero4();
#pragma unroll
  for (int kc = 0; kc < 4; kc++) {
    half8 af[2];
#pragma unroll
    for (int mt = 0; mt < 2; mt++) {
      int row = (w * 2 + mt) * 16 + (l & 15);
      int addr = (row * 256 + (kc << 6) + ((l >> 4) << 4)) ^ ((row & 7) << 4);
      af[mt] = *(const half8*)((const char*)ldsA + addr);
    }
#pragma unroll
    for (int nt = 0; nt < 8; nt++) {
      half8 bf = *(const half8*)&ldsW[(((nt << 2) | kc) * 64 + l) * 8];
      acc[0][nt] = __builtin_amdgcn_mfma_f32_16x16x32_f16(af[0], bf, acc[0][nt], 0, 0, 0);
      acc[1][nt] = __builtin_amdgcn_mfma_f32_16x16x32_f16(af[1], bf, acc[1][nt], 0, 0, 0);
    }
  }
  __syncthreads();  // all emb-tile reads done; ldsA reused for h-fragments

  // write h (+b_lin) into 32x32x16 B-frag layout: [tree][nt2][kc2][lane][8] f16
#pragma unroll
  for (int mt = 0; mt < 2; mt++) {
    const int Mt = w * 2 + mt, tree = Mt >> 1, kc2 = Mt & 1;
#pragma unroll
    for (int nt = 0; nt < 8; nt++) {
      const float bl = b_lin[nt * 16 + (l & 15)];
      const int nt2 = nt >> 1;
      const int ncol = ((nt & 1) << 4) + (l & 15);
#pragma unroll
      for (int reg = 0; reg < 4; reg++) {
        int rowrem = ((l >> 4) << 2) + reg;          // row within 16x16 C tile
        int l2 = ((rowrem >> 3) << 5) + ncol;
        int idx = (((((tree << 2) + nt2) << 1) + kc2) * 64 + l2) * 8 + (rowrem & 7);
        ldsA[idx] = (_Float16)(acc[mt][nt][reg] + bl);
      }
    }
  }
  __syncthreads();

  // per-tree subtree-sum: S[32][128] = anc(0/1) @ h  (32x32x16), wave w = tree w
  {
    const int tree = w;
    half8 ancf[2];
#pragma unroll
    for (int kc2 = 0; kc2 < 2; kc2++) {
      H8 u;
#pragma unroll
      for (int e = 0; e < 8; e++) {
        int n = (kc2 << 4) + ((l >> 5) << 3) + e;
        unsigned m = ldsAnc[(tree << 5) + n];
        u.h[e] = (_Float16)(float)((m >> (l & 31)) & 1u);
      }
      ancf[kc2] = u.h;
    }
    f32x16 acc2[4];
#pragma unroll
    for (int nt2 = 0; nt2 < 4; nt2++)
#pragma unroll
      for (int e = 0; e < 16; e++) acc2[nt2][e] = 0.f;
#pragma unroll
    for (int nt2 = 0; nt2 < 4; nt2++)
#pragma unroll
      for (int kc2 = 0; kc2 < 2; kc2++) {
        half8 bf = *(const half8*)&ldsA[(((((tree << 2) + nt2) << 1) + kc2) * 64 + l) * 8];
        acc2[nt2] = __builtin_amdgcn_mfma_f32_32x32x16_f16(ancf[kc2], bf, acc2[nt2], 0, 0, 0);
      }
    // max-pool over the 32 node rows -> stmt[row'][c], row' = t*64 + b
#pragma unroll
    for (int nt2 = 0; nt2 < 4; nt2++) {
      float m1 = acc2[nt2][0];
#pragma unroll
      for (int e = 1; e < 16; e++) m1 = fmaxf(m1, acc2[nt2][e]);
      m1 = fmaxf(m1, __shfl_xor(m1, 32));
      if (l < 32) {
        int g = blk * 4 + tree;                      // tree = b*64 + t
        int rowp = (g & 63) * 64 + (g >> 6);         // row' = t*64 + b
        stmt[(size_t)rowp * CDIM + (nt2 << 5) + l] = (_Float16)m1;
      }
    }
  }
}

// ---------------------------------------------------------------------------
// K2: gi[dir][t][col(384)][b(64)] = wih @ stmt_t^T + bias  (32x32x16 f16).
//     Operand-swapped so C lanes carry b -> coalesced 128B stores.
//     Block = (t, dir); stmt rows t*64..t*64+63 staged in LDS.
// ---------------------------------------------------------------------------
__global__ __launch_bounds__(256) void astnn_gi(
    const _Float16* __restrict__ stmt, const _Float16* __restrict__ wihfrag,
    const float* __restrict__ biasP, float* __restrict__ gi)
{
  __shared__ _Float16 ldsS[8192];  // 64 rows (b) x 128 (k) f16, swizzled
  const int tq = threadIdx.x, w = tq >> 6, l = tq & 63;
  const int tpos = blockIdx.x, dir = blockIdx.y;

  {
    const float4* src = (const float4*)(stmt + (size_t)tpos * 64 * CDIM);
#pragma unroll
    for (int i = 0; i < 4; i++) {
      int id = i * 256 + tq, row = id >> 4, ch = id & 15;
      float4 v = src[id];
      *(float4*)((char*)ldsS + ((row * 256 + ch * 16) ^ ((row & 7) << 4))) = v;
    }
  }
  half8 afr[3][8];   // wih A-frags: wave w owns col-tiles w*3+i
  {
    const half8* wf = (const half8*)wihfrag + dir * 6144;
#pragma unroll
    for (int i = 0; i < 3; i++) {
      int ct = w * 3 + i;
#pragma unroll
      for (int kc = 0; kc < 8; kc++) afr[i][kc] = wf[((ct << 3) + kc) * 64 + l];
    }
  }
  __syncthreads();

  f32x16 acc[2][3];  // [b-tile][col-tile]
#pragma unroll
  for (int bt = 0; bt < 2; bt++)
#pragma unroll
    for (int i = 0; i < 3; i++)
#pragma unroll
      for (int e = 0; e < 16; e++) acc[bt][i][e] = 0.f;

#pragma unroll
  for (int kc = 0; kc < 8; kc++) {
    half8 bfr[2];
#pragma unroll
    for (int bt = 0; bt < 2; bt++) {
      int row = (bt << 5) + (l & 31);               // b
      int kbyte = (kc << 5) + ((l >> 5) << 4);      // k*2 bytes
      bfr[bt] = *(const half8*)((const char*)ldsS +
                                ((row * 256 + kbyte) ^ ((row & 7) << 4)));
    }
#pragma unroll
    for (int i = 0; i < 3; i++)
#pragma unroll
      for (int bt = 0; bt < 2; bt++)
        acc[bt][i] = __builtin_amdgcn_mfma_f32_32x32x16_f16(afr[i][kc], bfr[bt],
                                                            acc[bt][i], 0, 0, 0);
  }

  float* gout = gi + (((size_t)dir * 64 + tpos) * 384) * 64;
#pragma unroll
  for (int i = 0; i < 3; i++) {
#pragma unroll
    for (int reg = 0; reg < 16; reg++) {
      int rowfrag = (reg & 3) + ((reg >> 2) << 3) + ((l >> 5) << 2);
      int col = (w * 3 + i) * 32 + rowfrag;
      float bias = biasP[dir * 384 + col];
#pragma unroll
      for (int bt = 0; bt < 2; bt++)
        gout[(size_t)col * 64 + (bt << 5) + (l & 31)] = acc[bt][i][reg] + bias;
    }
  }
}

// ---------------------------------------------------------------------------
// K3: bidirectional GRU recurrence, grid (4 batch-tiles, 2 dirs), 7 waves.
//     Wave w owns gate cols j=16w+(l&15); M=16 batch rows.
//     gi [t][col][b] -> 3 float4 loads/step via 4-deep ring with a
//     SCALAR-stepped prefetch pointer (60 main steps + 4-step epilogue).
//     LDS swizzle (row&12)<<3: h ds_write rows {0,4,8,12}+reg spread over
//     all 32 banks (the old (row&7)<<4 aliased rows r/r+8 -> 4-way write
//     conflicts, 896 conflict-cycles/step). Reads stay at the 8-cy minimum.
//     acc init = gi (r,z); bhh_n via constant h col 100 = 1.0;
//     double-buffered h in LDS; raw lgkmcnt+s_barrier (no vmcnt drain).
// ---------------------------------------------------------------------------
__global__ __launch_bounds__(448) void astnn_gru(
    const _Float16* __restrict__ whhfrag, const float* __restrict__ gi,
    float* __restrict__ pooled)
{
  __shared__ _Float16 hlds[4096];  // 2 x (16 rows x 128 cols f16, swizzled)
  const int t = threadIdx.x, w = t >> 6, l = t & 63;
  const int mb = blockIdx.x, dir = blockIdx.y;
  for (int i = t; i < 512; i += 448)          // zero BOTH buffers
    ((float4*)hlds)[i] = make_float4(0.f, 0.f, 0.f, 0.f);
  __syncthreads();
  if (t < 32) {                               // h col 100 = 1.0 (bhh_n carrier)
    int row = t & 15, buf = t >> 4;
    int addr = ((row * 256 + 200) ^ ((row & 12) << 3)) + (buf << 12);
    *(_Float16*)((char*)hlds + addr) = (_Float16)1.0f;
  }

  const int j = (w << 4) + (l & 15);
  const bool jv = (j < HDIM);
  const int rloc = (l >> 4) << 2;             // local row base: 0,4,8,12
  const int grow = (mb << 4) + rloc;          // global batch row base

  // hoisted LDS addresses (swizzle (row&12)<<3)
  int raddr[4], waddr[4];
  {
    int row = l & 15;
#pragma unroll
    for (int kc = 0; kc < 4; kc++)
      raddr[kc] = (row * 256 + (kc << 6) + ((l >> 4) << 4)) ^ ((row & 12) << 3);
#pragma unroll
    for (int reg = 0; reg < 4; reg++) {
      int rw = rloc + reg;
      waddr[reg] = (rw * 256 + (j << 1)) ^ ((rw & 12) << 3);
    }
  }
  // gi lane offsets (BYTES)
  int loffB0 = (((0 << 7) + j) * 64 + grow) * 4;
  int loffB1 = (((1 << 7) + j) * 64 + grow) * 4;
  int loffB2 = (((2 << 7) + j) * 64 + grow) * 4;
  const char* gseq = (const char*)gi + (size_t)dir * 1572864 * 4;

  half8 bfr[3][4];
  {
    const half8* wf = (const half8*)whhfrag + dir * 5376;
#pragma unroll
    for (int s = 0; s < 3; s++)
#pragma unroll
      for (int kc = 0; kc < 4; kc++)
        bfr[s][kc] = wf[(((s * 7 + w) << 2) + kc) * 64 + l];
  }

  float hreg[4], pool[4];
#pragma unroll
  for (int i = 0; i < 4; i++) { hreg[i] = 0.f; pool[i] = -3.0e38f; }

  // 4-deep gi prefetch ring; prefetch pointer stepped uniformly (SALU)
  const ptrdiff_t dstep = (ptrdiff_t)(dir ? -24576 : 24576) * 4;
  const char* pbase = gseq + (size_t)(dir ? 63 : 0) * 24576 * 4;
  float4 gp[4][3];
#pragma unroll
  for (int d = 0; d < 4; d++) {
    const char* p = pbase + d * dstep;
    gp[d][0] = *(const float4*)(p + loffB0);
    gp[d][1] = *(const float4*)(p + loffB1);
    gp[d][2] = *(const float4*)(p + loffB2);
  }
  const char* ppre = pbase + 4 * dstep;
  __syncthreads();

#define GRU_BODY(U, ROFF, WOFF, PF)                                             \
  {                                                                             \
    F4 u0, u1; u0.f = gp[U][0]; u1.f = gp[U][1];                                \
    f32x4 acc0 = u0.v, acc1 = u1.v, acc2 = zero4();                             \
    float4 g2 = gp[U][2];                                                       \
    if (PF) {                                                                   \
      gp[U][0] = *(const float4*)(ppre + loffB0);                               \
      gp[U][1] = *(const float4*)(ppre + loffB1);                               \
      gp[U][2] = *(const float4*)(ppre + loffB2);                               \
      ppre += dstep;                                                            \
    }                                                                           \
    _Pragma("unroll")                                                           \
    for (int kc = 0; kc < 4; kc++) {                                            \
      half8 af = *(const half8*)((const char*)hlds + raddr[kc] + (ROFF));       \
      acc0 = __builtin_amdgcn_mfma_f32_16x16x32_f16(af, bfr[0][kc], acc0, 0, 0, 0); \
      acc1 = __builtin_amdgcn_mfma_f32_16x16x32_f16(af, bfr[1][kc], acc1, 0, 0, 0); \
      acc2 = __builtin_amdgcn_mfma_f32_16x16x32_f16(af, bfr[2][kc], acc2, 0, 0, 0); \
    }                                                                           \
    _Pragma("unroll")                                                           \
    for (int reg = 0; reg < 4; reg++) {                                         \
      float r = sigmoidf_fast(acc0[reg]);                                       \
      float z = sigmoidf_fast(acc1[reg]);                                       \
      float n = tanhf_fast(fmaf(r, acc2[reg], ((const float*)&g2)[reg]));       \
      float hn = n + z * (hreg[reg] - n);                                       \
      hreg[reg] = hn;                                                           \
      pool[reg] = fmaxf(pool[reg], hn);                                         \
      if (jv)                                                                   \
        *(_Float16*)((char*)hlds + waddr[reg] + (WOFF)) = (_Float16)hn;         \
    }                                                                           \
    asm volatile("s_waitcnt lgkmcnt(0)" ::: "memory");                          \
    __builtin_amdgcn_s_barrier();                                               \
    __builtin_amdgcn_sched_barrier(0);                                          \
  }

#pragma unroll 1
  for (int it = 0; it < 15; ++it) {
    GRU_BODY(0, 0, 4096, 1)
    GRU_BODY(1, 4096, 0, 1)
    GRU_BODY(2, 0, 4096, 1)
    GRU_BODY(3, 4096, 0, 1)
  }
  // epilogue: steps 60..63, no prefetch
  GRU_BODY(0, 0, 4096, 0)
  GRU_BODY(1, 4096, 0, 0)
  GRU_BODY(2, 0, 4096, 0)
  GRU_BODY(3, 4096, 0, 0)
#undef GRU_BODY

  if (jv) {
#pragma unroll
    for (int reg = 0; reg < 4; reg++)
      pooled[((size_t)dir << 13) + ((size_t)(grow + reg) << 7) + j] = pool[reg];
  }
}

// ---------------------------------------------------------------------------
// K4: out[b][o] = [pooled_f | pooled_b] @ fc_w + fc_b
// ---------------------------------------------------------------------------
__global__ __launch_bounds__(128) void astnn_fc(
    const float* __restrict__ pooled, const float* __restrict__ fc_w,
    const float* __restrict__ fc_b, float* __restrict__ out)
{
  __shared__ float p[200];
  const int b = blockIdx.x, t = threadIdx.x;
  for (int i = t; i < 200; i += 128) {
    int d = i / 100, jj = i - d * 100;
    p[i] = pooled[((size_t)d << 13) + (b << 7) + jj];
  }
  __syncthreads();
  if (t < ODIM) {
    float a = fc_b[t];
#pragma unroll 8
    for (int k = 0; k < 200; k++) a = fmaf(p[k], fc_w[k * ODIM + t], a);
    out[b * ODIM + t] = a;
  }
}

// ---------------------------------------------------------------------------
extern "C" void kernel_launch(void* const* d_in, const int* in_sizes, int n_in,
                              void* d_out, int out_size, void* d_ws, size_t ws_size,
                              hipStream_t stream)
{
  const int* node_ids = (const int*)d_in[0];
  const int* parent   = (const int*)d_in[1];
  // d_in[2]=level, d_in[3]=tree_id: unused (decreasing-index order suffices)
  const float* emb    = (const float*)d_in[4];
  const float* W_lin  = (const float*)d_in[5];
  const float* b_lin  = (const float*)d_in[6];
  const float* wihf   = (const float*)d_in[7];
  const float* whhf   = (const float*)d_in[8];
  const float* bihf   = (const float*)d_in[9];
  const float* bhhf   = (const float*)d_in[10];
  const float* wihb   = (const float*)d_in[11];
  const float* whhb   = (const float*)d_in[12];
  const float* bihb   = (const float*)d_in[13];
  const float* bhhb   = (const float*)d_in[14];
  const float* fc_w   = (const float*)d_in[15];
  const float* fc_b   = (const float*)d_in[16];

  char* ws = (char*)d_ws;
  _Float16* wfrag   = (_Float16*)(ws + OFF_WFRAG);
  _Float16* wihfrag = (_Float16*)(ws + OFF_WIH);
  _Float16* whhfrag = (_Float16*)(ws + OFF_WHH);
  float* biasP      = (float*)(ws + OFF_BIASP);
  _Float16* stmt    = (_Float16*)(ws + OFF_STMT);
  float* gi         = (float*)(ws + OFF_GI);
  float* pooled     = (float*)(ws + OFF_POOL);
  float* out        = (float*)d_out;

  astnn_prep<<<102, 256, 0, stream>>>(W_lin, wihf, whhf, bihf, bhhf,
                                      wihb, whhb, bihb, bhhb,
                                      wfrag, wihfrag, whhfrag, biasP);
  astnn_tree<<<1024, 256, 0, stream>>>(node_ids, parent, emb, b_lin, wfrag, stmt);
  astnn_gi<<<dim3(64, 2), 256, 0, stream>>>(stmt, wihfrag, biasP, gi);
  astnn_gru<<<dim3(4, 2), 448, 0, stream>>>(whhfrag, gi, pooled);
  astnn_fc<<<64, 128, 0, stream>>>(pooled, fc_w, fc_b, out);
}

// Round 7
// 85.571 us; speedup vs baseline: 1.3416x; 1.3416x over previous
//
#include <hip/hip_runtime.h>

typedef _Float16 half8 __attribute__((ext_vector_type(8)));
typedef float f32x4 __attribute__((ext_vector_type(4)));
typedef float f32x16 __attribute__((ext_vector_type(16)));

union H8 { half8 h; float4 f; };
union F4 { float4 f; f32x4 v; };

#define EDIM 128
#define CDIM 128
#define HDIM 100
#define ODIM 104

// workspace offsets (bytes), all 256-aligned; total = 14,102,528 bytes
#define OFF_WFRAG  0u          // W_lin B-frags (16x16x32):   8*4*64*8*2  = 32768
#define OFF_WIH    32768u      // wih A-frags (32x32x16):  2*12*8*64*8*2  = 196608
#define OFF_WHH    229376u     // whh B-frags (16x16x32):  2*21*4*64*8*2  = 172032
#define OFF_BIASP  401408u     // gi bias (bih + bhh_{r,z}): 2*384*4      = 3072
#define OFF_BHHN   404480u     // (unused)                                = 1024
#define OFF_STMT   405504u     // stmt f16 [t*64+b][128]:    4096*128*2   = 1048576
#define OFF_GI     1454080u    // gi fp32 [dir][t][col][b]: 2*64*384*64*4 = 12582912
#define OFF_POOL   14036992u   // pooled fp32: 2*64*128*4                 = 65536

__device__ inline f32x4 zero4() { f32x4 z = {0.f, 0.f, 0.f, 0.f}; return z; }

// minimal-op transcendentals (guaranteed v_exp/v_rcp, no ocml fixup chains)
__device__ inline float fast_exp2(float x) {
  float r; asm("v_exp_f32 %0, %1" : "=v"(r) : "v"(x)); return r;
}
__device__ inline float fast_rcp(float x) {
  float r; asm("v_rcp_f32 %0, %1" : "=v"(r) : "v"(x)); return r;
}
__device__ inline float sigmoid_f(float x) {        // 1/(1+e^-x)
  return fast_rcp(1.f + fast_exp2(x * -1.44269504f));
}
__device__ inline float tanh_f(float x) {           // 1 - 2/(1+e^(2x))
  float e = fast_exp2(x * 2.88539008f);
  return fmaf(fast_rcp(1.f + e), -2.f, 1.f);
}

// K3 LDS swizzle: read 2-way-free AND write conflict-free (see r7 notes)
#define HSWZ(row) ((((row) & 3) << 4) ^ (((row) & 12) << 3))

// ---------------------------------------------------------------------------
// K0: convert weights to f16 MFMA fragment layouts + fold biases (runs every call)
// ---------------------------------------------------------------------------
__global__ __launch_bounds__(256) void astnn_prep(
    const float* __restrict__ W_lin,
    const float* __restrict__ wihf, const float* __restrict__ whhf,
    const float* __restrict__ bihf, const float* __restrict__ bhhf,
    const float* __restrict__ wihb, const float* __restrict__ whhb,
    const float* __restrict__ bihb, const float* __restrict__ bhhb,
    _Float16* __restrict__ wfrag, _Float16* __restrict__ wihfrag,
    _Float16* __restrict__ whhfrag, float* __restrict__ biasP)
{
  int gid = blockIdx.x * 256 + threadIdx.x;
  if (gid < 2048) {
    // W_lin -> 16x16x32 B-frags: B[k][n], lane l: n=l&15, k=kc*32+((l>>4)<<3)+e
    int i = gid, l = i & 63, kc = (i >> 6) & 3, nt = i >> 8;
    int n = (nt << 4) + (l & 15);
    int kb = (kc << 5) + ((l >> 4) << 3);
#pragma unroll
    for (int e = 0; e < 8; e++)
      wfrag[i * 8 + e] = (_Float16)W_lin[(kb + e) * CDIM + n];
  } else if (gid < 14336) {
    // wih -> 32x32x16 frags usable as A (m=l&31, k=kc*16+((l>>5)<<3)+e):
    // value = wih[col=m][k]; cols padded per-section to 128 (12 tiles of 32)
    int i = gid - 2048, l = i & 63, kc = (i >> 6) & 7;
    int rest = i >> 9, nt = rest % 12, d = rest / 12;
    const float* wih = d ? wihb : wihf;
    int n = (nt << 5) + (l & 31), s = n >> 7, j = n & 127;
    int kb = (kc << 4) + ((l >> 5) << 3);
#pragma unroll
    for (int e = 0; e < 8; e++) {
      float v = (j < HDIM) ? wih[(s * HDIM + j) * CDIM + (kb + e)] : 0.f;
      wihfrag[i * 8 + e] = (_Float16)v;
    }
  } else if (gid < 25088) {
    // whh -> 16x16x32 B-frags: lane l: n=l&15, k=kc*32+((l>>4)<<3)+e
    // N padded per-section to 112 (3*112=336, 21 tiles of 16), K padded to 128
    // k==HDIM row of the n-section (s==2) carries bhh_n (h col 100 is const 1.0)
    int i = gid - 14336, l = i & 63, kc = (i >> 6) & 3;
    int rest = i >> 8, nt = rest % 21, d = rest / 21;
    const float* whh = d ? whhb : whhf;
    const float* bhh = d ? bhhb : bhhf;
    int n = (nt << 4) + (l & 15), s = n / 112, j = n - 112 * s;
    int kb = (kc << 5) + ((l >> 4) << 3);
#pragma unroll
    for (int e = 0; e < 8; e++) {
      int k = kb + e;
      float v = 0.f;
      if (j < HDIM) {
        if (k < HDIM) v = whh[(s * HDIM + j) * HDIM + k];
        else if (k == HDIM && s == 2) v = bhh[2 * HDIM + j];
      }
      whhfrag[i * 8 + e] = (_Float16)v;
    }
  } else if (gid < 25856) {
    // biasP[d][384] = bih[g] + (s<2 ? bhh[g] : 0), pad = 0
    int i = gid - 25088, d = i / 384, col = i % 384, s = col >> 7, j = col & 127;
    const float* bih = d ? bihb : bihf;
    const float* bhh = d ? bhhb : bhhf;
    float v = 0.f;
    if (j < HDIM) { v = bih[s * HDIM + j]; if (s < 2) v += bhh[s * HDIM + j]; }
    biasP[i] = v;
  }
}

// ---------------------------------------------------------------------------
// K1: per-block 4 trees (128 nodes): gather emb -> f16 LDS, MFMA x W_lin (+b),
//     subtree-sum via ancestor-bitmask MFMA, max-pool -> stmt (f16).
//     stmt stored in row' = t*64 + b order (tree g = b*64+t).
// ---------------------------------------------------------------------------
__global__ __launch_bounds__(256, 2) void astnn_tree(
    const int* __restrict__ node_ids, const int* __restrict__ parent,
    const float* __restrict__ emb, const float* __restrict__ b_lin,
    const _Float16* __restrict__ wfrag, _Float16* __restrict__ stmt)
{
  __shared__ _Float16 ldsW[16384];   // 32KB: W B-frags (linear frag order)
  __shared__ _Float16 ldsA[16384];   // 32KB: emb tile (swizzled), reused for h-frags
  __shared__ int ldsPar[128];
  __shared__ unsigned ldsAnc[128];

  const int t = threadIdx.x, blk = blockIdx.x;
  const int w = t >> 6, l = t & 63;
  const int base = blk * 128;

  if (t < 128) ldsPar[t] = parent[base + t] & 31;  // trees are 32-aligned globally

  {  // stage W fragments (32KB linear copy)
    const float4* wsrc = (const float4*)wfrag;
#pragma unroll
    for (int i = 0; i < 8; i++) ((float4*)ldsW)[i * 256 + t] = wsrc[i * 256 + t];
  }

  {  // gather embedding rows -> f16, swizzled row-major [128][128]
    const int r = t >> 1, hf = t & 1;
    const int nid = node_ids[base + r];
    const float4* erow = (const float4*)(emb + (size_t)nid * EDIM) + hf * 16;
#pragma unroll
    for (int b2 = 0; b2 < 2; b2++) {
      float4 stage[8];
#pragma unroll
      for (int i = 0; i < 8; i++) stage[i] = erow[b2 * 8 + i];
#pragma unroll
      for (int c4 = 0; c4 < 4; c4++) {
        H8 u;
#pragma unroll
        for (int e = 0; e < 8; e++)
          u.h[e] = (_Float16)(((const float*)&stage[0])[c4 * 8 + e]);
        int c = b2 * 4 + c4;
        int addr = (r * 256 + hf * 128 + c * 16) ^ ((r & 7) << 4);
        *(float4*)((char*)ldsA + addr) = u.f;
      }
    }
  }
  __syncthreads();

  // ancestor-mask build: A[n] = ancestors-or-self bitmask (chain walk, depth<=10)
  if (t < 128) {
    int tree = t >> 5;
    unsigned mask = 0;
    int cur = t & 31;
#pragma unroll
    for (int it = 0; it < 11; ++it) { mask |= (1u << cur); cur = ldsPar[tree * 32 + cur]; }
    ldsAnc[t] = mask;
  }
  __syncthreads();

  // GEMM: h[128][128] = emb_tile @ W  (16x16x32 f16), wave w owns M-tiles 2w,2w+1
  f32x4 acc[2][8];
#pragma unroll
  for (int mt = 0; mt < 2; mt++)
#pragma unroll
    for (int nt = 0; nt < 8; nt++) acc[mt][nt] = zero4();
#pragma unroll
  for (int kc = 0; kc < 4; kc++) {
    half8 af[2];
#pragma unroll
    for (int mt = 0; mt < 2; mt++) {
      int row = (w * 2 + mt) * 16 + (l & 15);
      int addr = (row * 256 + (kc << 6) + ((l >> 4) << 4)) ^ ((row & 7) << 4);
      af[mt] = *(const half8*)((const char*)ldsA + addr);
    }
#pragma unroll
    for (int nt = 0; nt < 8; nt++) {
      half8 bf = *(const half8*)&ldsW[(((nt << 2) | kc) * 64 + l) * 8];
      acc[0][nt] = __builtin_amdgcn_mfma_f32_16x16x32_f16(af[0], bf, acc[0][nt], 0, 0, 0);
      acc[1][nt] = __builtin_amdgcn_mfma_f32_16x16x32_f16(af[1], bf, acc[1][nt], 0, 0, 0);
    }
  }
  __syncthreads();  // all emb-tile reads done; ldsA reused for h-fragments

  // write h (+b_lin) into 32x32x16 B-frag layout: [tree][nt2][kc2][lane][8] f16
#pragma unroll
  for (int mt = 0; mt < 2; mt++) {
    const int Mt = w * 2 + mt, tree = Mt >> 1, kc2 = Mt & 1;
#pragma unroll
    for (int nt = 0; nt < 8; nt++) {
      const float bl = b_lin[nt * 16 + (l & 15)];
      const int nt2 = nt >> 1;
      const int ncol = ((nt & 1) << 4) + (l & 15);
#pragma unroll
      for (int reg = 0; reg < 4; reg++) {
        int rowrem = ((l >> 4) << 2) + reg;          // row within 16x16 C tile
        int l2 = ((rowrem >> 3) << 5) + ncol;
        int idx = (((((tree << 2) + nt2) << 1) + kc2) * 64 + l2) * 8 + (rowrem & 7);
        ldsA[idx] = (_Float16)(acc[mt][nt][reg] + bl);
      }
    }
  }
  __syncthreads();

  // per-tree subtree-sum: S[32][128] = anc(0/1) @ h  (32x32x16), wave w = tree w
  {
    const int tree = w;
    half8 ancf[2];
#pragma unroll
    for (int kc2 = 0; kc2 < 2; kc2++) {
      H8 u;
#pragma unroll
      for (int e = 0; e < 8; e++) {
        int n = (kc2 << 4) + ((l >> 5) << 3) + e;
        unsigned m = ldsAnc[(tree << 5) + n];
        u.h[e] = (_Float16)(float)((m >> (l & 31)) & 1u);
      }
      ancf[kc2] = u.h;
    }
    f32x16 acc2[4];
#pragma unroll
    for (int nt2 = 0; nt2 < 4; nt2++)
#pragma unroll
      for (int e = 0; e < 16; e++) acc2[nt2][e] = 0.f;
#pragma unroll
    for (int nt2 = 0; nt2 < 4; nt2++)
#pragma unroll
      for (int kc2 = 0; kc2 < 2; kc2++) {
        half8 bf = *(const half8*)&ldsA[(((((tree << 2) + nt2) << 1) + kc2) * 64 + l) * 8];
        acc2[nt2] = __builtin_amdgcn_mfma_f32_32x32x16_f16(ancf[kc2], bf, acc2[nt2], 0, 0, 0);
      }
    // max-pool over the 32 node rows -> stmt[row'][c], row' = t*64 + b
#pragma unroll
    for (int nt2 = 0; nt2 < 4; nt2++) {
      float m1 = acc2[nt2][0];
#pragma unroll
      for (int e = 1; e < 16; e++) m1 = fmaxf(m1, acc2[nt2][e]);
      m1 = fmaxf(m1, __shfl_xor(m1, 32));
      if (l < 32) {
        int g = blk * 4 + tree;                      // tree = b*64 + t
        int rowp = (g & 63) * 64 + (g >> 6);         // row' = t*64 + b
        stmt[(size_t)rowp * CDIM + (nt2 << 5) + l] = (_Float16)m1;
      }
    }
  }
}

// ---------------------------------------------------------------------------
// K2: gi[dir][t][col(384)][b(64)] = wih @ stmt_t^T + bias  (32x32x16 f16).
//     Operand-swapped so C lanes carry b -> coalesced 128B stores.
//     Block = (t, dir); stmt rows t*64..t*64+63 staged in LDS.
// ---------------------------------------------------------------------------
__global__ __launch_bounds__(256) void astnn_gi(
    const _Float16* __restrict__ stmt, const _Float16* __restrict__ wihfrag,
    const float* __restrict__ biasP, float* __restrict__ gi)
{
  __shared__ _Float16 ldsS[8192];  // 64 rows (b) x 128 (k) f16, swizzled
  const int tq = threadIdx.x, w = tq >> 6, l = tq & 63;
  const int tpos = blockIdx.x, dir = blockIdx.y;

  {
    const float4* src = (const float4*)(stmt + (size_t)tpos * 64 * CDIM);
#pragma unroll
    for (int i = 0; i < 4; i++) {
      int id = i * 256 + tq, row = id >> 4, ch = id & 15;
      float4 v = src[id];
      *(float4*)((char*)ldsS + ((row * 256 + ch * 16) ^ ((row & 7) << 4))) = v;
    }
  }
  half8 afr[3][8];   // wih A-frags: wave w owns col-tiles w*3+i
  {
    const half8* wf = (const half8*)wihfrag + dir * 6144;
#pragma unroll
    for (int i = 0; i < 3; i++) {
      int ct = w * 3 + i;
#pragma unroll
      for (int kc = 0; kc < 8; kc++) afr[i][kc] = wf[((ct << 3) + kc) * 64 + l];
    }
  }
  __syncthreads();

  f32x16 acc[2][3];  // [b-tile][col-tile]
#pragma unroll
  for (int bt = 0; bt < 2; bt++)
#pragma unroll
    for (int i = 0; i < 3; i++)
#pragma unroll
      for (int e = 0; e < 16; e++) acc[bt][i][e] = 0.f;

#pragma unroll
  for (int kc = 0; kc < 8; kc++) {
    half8 bfr[2];
#pragma unroll
    for (int bt = 0; bt < 2; bt++) {
      int row = (bt << 5) + (l & 31);               // b
      int kbyte = (kc << 5) + ((l >> 5) << 4);      // k*2 bytes
      bfr[bt] = *(const half8*)((const char*)ldsS +
                                ((row * 256 + kbyte) ^ ((row & 7) << 4)));
    }
#pragma unroll
    for (int i = 0; i < 3; i++)
#pragma unroll
      for (int bt = 0; bt < 2; bt++)
        acc[bt][i] = __builtin_amdgcn_mfma_f32_32x32x16_f16(afr[i][kc], bfr[bt],
                                                            acc[bt][i], 0, 0, 0);
  }

  float* gout = gi + (((size_t)dir * 64 + tpos) * 384) * 64;
#pragma unroll
  for (int i = 0; i < 3; i++) {
#pragma unroll
    for (int reg = 0; reg < 16; reg++) {
      int rowfrag = (reg & 3) + ((reg >> 2) << 3) + ((l >> 5) << 2);
      int col = (w * 3 + i) * 32 + rowfrag;
      float bias = biasP[dir * 384 + col];
#pragma unroll
      for (int bt = 0; bt < 2; bt++)
        gout[(size_t)col * 64 + (bt << 5) + (l & 31)] = acc[bt][i][reg] + bias;
    }
  }
}

// ---------------------------------------------------------------------------
// K3: bidirectional GRU recurrence, grid (4 batch-tiles, 2 dirs), 7 waves.
//     Wave w owns gate cols j=16w+(l&15); M=16 batch rows.
//     gi [t][col][b] -> 3 float4 loads/step via 4-deep ring, SCALAR-stepped
//     prefetch pointer (60 main + 4 epilogue). LDS swizzle HSWZ makes the
//     h ds_read 2-way-free AND the ds_write conflict-free. Gate math uses
//     raw v_exp/v_rcp. acc init = gi (r,z); bhh_n via constant h col 100=1.
// ---------------------------------------------------------------------------
__global__ __launch_bounds__(448) void astnn_gru(
    const _Float16* __restrict__ whhfrag, const float* __restrict__ gi,
    float* __restrict__ pooled)
{
  __shared__ _Float16 hlds[4096];  // 2 x (16 rows x 128 cols f16, swizzled)
  const int t = threadIdx.x, w = t >> 6, l = t & 63;
  const int mb = blockIdx.x, dir = blockIdx.y;
  for (int i = t; i < 512; i += 448)          // zero BOTH buffers
    ((float4*)hlds)[i] = make_float4(0.f, 0.f, 0.f, 0.f);
  __syncthreads();
  if (t < 32) {                               // h col 100 = 1.0 (bhh_n carrier)
    int row = t & 15, buf = t >> 4;
    int addr = ((row * 256 + 200) ^ HSWZ(row)) + (buf << 12);
    *(_Float16*)((char*)hlds + addr) = (_Float16)1.0f;
  }

  const int j = (w << 4) + (l & 15);
  const bool jv = (j < HDIM);
  const int rloc = (l >> 4) << 2;             // local row base: 0,4,8,12
  const int grow = (mb << 4) + rloc;          // global batch row base

  // hoisted LDS addresses (swizzle HSWZ)
  int raddr[4], waddr[4];
  {
    int row = l & 15;
#pragma unroll
    for (int kc = 0; kc < 4; kc++)
      raddr[kc] = (row * 256 + (kc << 6) + ((l >> 4) << 4)) ^ HSWZ(row);
#pragma unroll
    for (int reg = 0; reg < 4; reg++) {
      int rw = rloc + reg;
      waddr[reg] = (rw * 256 + (j << 1)) ^ HSWZ(rw);
    }
  }
  // gi lane offsets (BYTES)
  int loffB0 = (((0 << 7) + j) * 64 + grow) * 4;
  int loffB1 = (((1 << 7) + j) * 64 + grow) * 4;
  int loffB2 = (((2 << 7) + j) * 64 + grow) * 4;
  const char* gseq = (const char*)gi + (size_t)dir * 1572864 * 4;

  half8 bfr[3][4];
  {
    const half8* wf = (const half8*)whhfrag + dir * 5376;
#pragma unroll
    for (int s = 0; s < 3; s++)
#pragma unroll
      for (int kc = 0; kc < 4; kc++)
        bfr[s][kc] = wf[(((s * 7 + w) << 2) + kc) * 64 + l];
  }

  float hreg[4], pool[4];
#pragma unroll
  for (int i = 0; i < 4; i++) { hreg[i] = 0.f; pool[i] = -3.0e38f; }

  // 4-deep gi prefetch ring; prefetch pointer stepped uniformly (SALU)
  const ptrdiff_t dstep = (ptrdiff_t)(dir ? -24576 : 24576) * 4;
  const char* pbase = gseq + (size_t)(dir ? 63 : 0) * 24576 * 4;
  float4 gp[4][3];
#pragma unroll
  for (int d = 0; d < 4; d++) {
    const char* p = pbase + d * dstep;
    gp[d][0] = *(const float4*)(p + loffB0);
    gp[d][1] = *(const float4*)(p + loffB1);
    gp[d][2] = *(const float4*)(p + loffB2);
  }
  const char* ppre = pbase + 4 * dstep;
  __syncthreads();

#define GRU_BODY(U, ROFF, WOFF, PF)                                             \
  {                                                                             \
    F4 u0, u1; u0.f = gp[U][0]; u1.f = gp[U][1];                                \
    f32x4 acc0 = u0.v, acc1 = u1.v, acc2 = zero4();                             \
    float4 g2 = gp[U][2];                                                       \
    if (PF) {                                                                   \
      gp[U][0] = *(const float4*)(ppre + loffB0);                               \
      gp[U][1] = *(const float4*)(ppre + loffB1);                               \
      gp[U][2] = *(const float4*)(ppre + loffB2);                               \
      ppre += dstep;                                                            \
    }                                                                           \
    _Pragma("unroll")                                                           \
    for (int kc = 0; kc < 4; kc++) {                                            \
      half8 af = *(const half8*)((const char*)hlds + raddr[kc] + (ROFF));       \
      acc0 = __builtin_amdgcn_mfma_f32_16x16x32_f16(af, bfr[0][kc], acc0, 0, 0, 0); \
      acc1 = __builtin_amdgcn_mfma_f32_16x16x32_f16(af, bfr[1][kc], acc1, 0, 0, 0); \
      acc2 = __builtin_amdgcn_mfma_f32_16x16x32_f16(af, bfr[2][kc], acc2, 0, 0, 0); \
    }                                                                           \
    _Pragma("unroll")                                                           \
    for (int reg = 0; reg < 4; reg++) {                                         \
      float r = sigmoid_f(acc0[reg]);                                           \
      float z = sigmoid_f(acc1[reg]);                                           \
      float n = tanh_f(fmaf(r, acc2[reg], ((const float*)&g2)[reg]));           \
      float hn = n + z * (hreg[reg] - n);                                       \
      hreg[reg] = hn;                                                           \
      pool[reg] = fmaxf(pool[reg], hn);                                         \
      if (jv)                                                                   \
        *(_Float16*)((char*)hlds + waddr[reg] + (WOFF)) = (_Float16)hn;         \
    }                                                                           \
    asm volatile("s_waitcnt lgkmcnt(0)" ::: "memory");                          \
    __builtin_amdgcn_s_barrier();                                               \
    __builtin_amdgcn_sched_barrier(0);                                          \
  }

#pragma unroll 1
  for (int it = 0; it < 15; ++it) {
    GRU_BODY(0, 0, 4096, 1)
    GRU_BODY(1, 4096, 0, 1)
    GRU_BODY(2, 0, 4096, 1)
    GRU_BODY(3, 4096, 0, 1)
  }
  // epilogue: steps 60..63, no prefetch
  GRU_BODY(0, 0, 4096, 0)
  GRU_BODY(1, 4096, 0, 0)
  GRU_BODY(2, 0, 4096, 0)
  GRU_BODY(3, 4096, 0, 0)
#undef GRU_BODY

  if (jv) {
#pragma unroll
    for (int reg = 0; reg < 4; reg++)
      pooled[((size_t)dir << 13) + ((size_t)(grow + reg) << 7) + j] = pool[reg];
  }
}

// ---------------------------------------------------------------------------
// K4: out[b][o] = [pooled_f | pooled_b] @ fc_w + fc_b
// ---------------------------------------------------------------------------
__global__ __launch_bounds__(128) void astnn_fc(
    const float* __restrict__ pooled, const float* __restrict__ fc_w,
    const float* __restrict__ fc_b, float* __restrict__ out)
{
  __shared__ float p[200];
  const int b = blockIdx.x, t = threadIdx.x;
  for (int i = t; i < 200; i += 128) {
    int d = i / 100, jj = i - d * 100;
    p[i] = pooled[((size_t)d << 13) + (b << 7) + jj];
  }
  __syncthreads();
  if (t < ODIM) {
    float a = fc_b[t];
#pragma unroll 8
    for (int k = 0; k < 200; k++) a = fmaf(p[k], fc_w[k * ODIM + t], a);
    out[b * ODIM + t] = a;
  }
}

// ---------------------------------------------------------------------------
extern "C" void kernel_launch(void* const* d_in, const int* in_sizes, int n_in,
                              void* d_out, int out_size, void* d_ws, size_t ws_size,
                              hipStream_t stream)
{
  const int* node_ids = (const int*)d_in[0];
  const int* parent   = (const int*)d_in[1];
  // d_in[2]=level, d_in[3]=tree_id: unused (decreasing-index order suffices)
  const float* emb    = (const float*)d_in[4];
  const float* W_lin  = (const float*)d_in[5];
  const float* b_lin  = (const float*)d_in[6];
  const float* wihf   = (const float*)d_in[7];
  const float* whhf   = (const float*)d_in[8];
  const float* bihf   = (const float*)d_in[9];
  const float* bhhf   = (const float*)d_in[10];
  const float* wihb   = (const float*)d_in[11];
  const float* whhb   = (const float*)d_in[12];
  const float* bihb   = (const float*)d_in[13];
  const float* bhhb   = (const float*)d_in[14];
  const float* fc_w   = (const float*)d_in[15];
  const float* fc_b   = (const float*)d_in[16];

  char* ws = (char*)d_ws;
  _Float16* wfrag   = (_Float16*)(ws + OFF_WFRAG);
  _Float16* wihfrag = (_Float16*)(ws + OFF_WIH);
  _Float16* whhfrag = (_Float16*)(ws + OFF_WHH);
  float* biasP      = (float*)(ws + OFF_BIASP);
  _Float16* stmt    = (_Float16*)(ws + OFF_STMT);
  float* gi         = (float*)(ws + OFF_GI);
  float* pooled     = (float*)(ws + OFF_POOL);
  float* out        = (float*)d_out;

  astnn_prep<<<102, 256, 0, stream>>>(W_lin, wihf, whhf, bihf, bhhf,
                                      wihb, whhb, bihb, bhhb,
                                      wfrag, wihfrag, whhfrag, biasP);
  astnn_tree<<<1024, 256, 0, stream>>>(node_ids, parent, emb, b_lin, wfrag, stmt);
  astnn_gi<<<dim3(64, 2), 256, 0, stream>>>(stmt, wihfrag, biasP, gi);
  astnn_gru<<<dim3(4, 2), 448, 0, stream>>>(whhfrag, gi, pooled);
  astnn_fc<<<64, 128, 0, stream>>>(pooled, fc_w, fc_b, out);
}